// Round 1
// baseline (119.820 us; speedup 1.0000x reference)
//
#include <hip/hip_runtime.h>

constexpr int Wd = 512;
constexpr int PLANE = 512 * 512;

__device__ __forceinline__ int swz(int b) { return b ^ ((b >> 3) & 7); }

// ---------------- kernel 1: per-plane-segment min/max partials ----------------
__global__ __launch_bounds__(256) void minmax_part(const float* __restrict__ pred,
                                                   const float* __restrict__ targ,
                                                   float* __restrict__ pmx,
                                                   float* __restrict__ pmn) {
    int bx = blockIdx.x;
    int plane = bx >> 3, seg = bx & 7;
    size_t base = (size_t)plane * PLANE + (size_t)seg * 32768;
    const float4* p4 = reinterpret_cast<const float4*>(pred + base);
    const float4* t4 = reinterpret_cast<const float4*>(targ + base);
    float mx = -3.0e38f, mn = 3.0e38f;
    for (int i = threadIdx.x; i < 8192; i += 256) {
        float4 a = p4[i], b = t4[i];
        mx = fmaxf(mx, fmaxf(fmaxf(fmaxf(a.x, b.x), fmaxf(a.y, b.y)),
                             fmaxf(fmaxf(a.z, b.z), fmaxf(a.w, b.w))));
        mn = fminf(mn, fminf(fminf(fminf(a.x, b.x), fminf(a.y, b.y)),
                             fminf(fminf(a.z, b.z), fminf(a.w, b.w))));
    }
    #pragma unroll
    for (int off = 32; off; off >>= 1) {
        mx = fmaxf(mx, __shfl_down(mx, off));
        mn = fminf(mn, __shfl_down(mn, off));
    }
    __shared__ float smx[4], smn[4];
    int wid = threadIdx.x >> 6, lane = threadIdx.x & 63;
    if (lane == 0) { smx[wid] = mx; smn[wid] = mn; }
    __syncthreads();
    if (threadIdx.x == 0) {
        pmx[bx] = fmaxf(fmaxf(smx[0], smx[1]), fmaxf(smx[2], smx[3]));
        pmn[bx] = fminf(fminf(smn[0], smn[1]), fminf(smn[2], smn[3]));
    }
}

// ---------------- kernel 2: finalize c1/c2 per plane ----------------
__global__ void minmax_fin(const float* __restrict__ pmx, const float* __restrict__ pmn,
                           float* __restrict__ c1s, float* __restrict__ c2s, int planes) {
    int p = blockIdx.x * blockDim.x + threadIdx.x;
    if (p < planes) {
        float mx = -3.0e38f, mn = 3.0e38f;
        for (int s = 0; s < 8; ++s) {
            mx = fmaxf(mx, pmx[p * 8 + s]);
            mn = fminf(mn, pmn[p * 8 + s]);
        }
        float dr = fmaxf(mx - mn, 1e-6f);
        float a = 0.01f * dr, b = 0.03f * dr;
        c1s[p] = a * a;
        c2s[p] = b * b;
    }
}

// ---------------- kernel 3: fused separable SSIM ----------------
// Grid: planes*8 blocks. Block: 256 threads = 4 waves. Each wave handles 16
// output rows of one plane; lane c owns columns 8c..8c+7. Vertical 11-row box
// sums of {p,t,pp,tt,pt} kept as running sums in registers (leaving row
// re-read from global -> L1/L2 hit). Horizontal 11-col box sum done through a
// wave-private, XOR-swizzled LDS row buffer with sliding sums.
__global__ __launch_bounds__(256) void ssim_main(const float* __restrict__ pred,
                                                 const float* __restrict__ targ,
                                                 const float* __restrict__ c1s,
                                                 const float* __restrict__ c2s,
                                                 float* __restrict__ parts) {
    __shared__ __align__(16) float lds[4 * 5 * 512];  // 40 KB: 4 waves x 5 q x 512 cols
    __shared__ float red[4];
    int bx = blockIdx.x;
    int plane = bx >> 3, tile = bx & 7;
    int wid = threadIdx.x >> 6, c = threadIdx.x & 63;
    const float c1 = c1s[plane], c2 = c2s[plane];
    const float* P = pred + (size_t)plane * PLANE;
    const float* T = targ + (size_t)plane * PLANE;
    float* L = lds + wid * (5 * 512);
    int r0 = tile * 64 + wid * 16;  // first output row of this wave

    float vsP[8], vsT[8], vsPP[8], vsTT[8], vsPT[8];
    #pragma unroll
    for (int k = 0; k < 8; ++k) { vsP[k] = 0; vsT[k] = 0; vsPP[k] = 0; vsTT[k] = 0; vsPT[k] = 0; }

    auto acc = [&](int r, float s) {
        if ((unsigned)r < 512u) {
            const float4* prow = reinterpret_cast<const float4*>(P + (size_t)r * Wd);
            const float4* trow = reinterpret_cast<const float4*>(T + (size_t)r * Wd);
            float4 a0 = prow[2 * c], a1 = prow[2 * c + 1];
            float4 b0 = trow[2 * c], b1 = trow[2 * c + 1];
            float pa[8] = {a0.x, a0.y, a0.z, a0.w, a1.x, a1.y, a1.z, a1.w};
            float tb[8] = {b0.x, b0.y, b0.z, b0.w, b1.x, b1.y, b1.z, b1.w};
            #pragma unroll
            for (int k = 0; k < 8; ++k) {
                float sp = s * pa[k], st = s * tb[k];
                vsP[k]  += sp;
                vsT[k]  += st;
                vsPP[k] += sp * pa[k];
                vsTT[k] += st * tb[k];
                vsPT[k] += sp * tb[k];
            }
        }
    };

    // init vertical window: rows r0-5 .. r0+4
    for (int r = r0 - 5; r <= r0 + 4; ++r) acc(r, 1.0f);

    float lsum = 0.0f;
    for (int it = 0; it < 16; ++it) {
        int orow = r0 + it;
        acc(orow + 5, 1.0f);  // window now rows orow-5..orow+5

        // write vertical sums to wave-private LDS, swizzled at 16B-block level
        float4* L0 = reinterpret_cast<float4*>(L);
        int b0i = swz(2 * c), b1i = swz(2 * c + 1);
        L0[0 * 128 + b0i] = make_float4(vsP[0], vsP[1], vsP[2], vsP[3]);
        L0[0 * 128 + b1i] = make_float4(vsP[4], vsP[5], vsP[6], vsP[7]);
        L0[1 * 128 + b0i] = make_float4(vsT[0], vsT[1], vsT[2], vsT[3]);
        L0[1 * 128 + b1i] = make_float4(vsT[4], vsT[5], vsT[6], vsT[7]);
        L0[2 * 128 + b0i] = make_float4(vsPP[0], vsPP[1], vsPP[2], vsPP[3]);
        L0[2 * 128 + b1i] = make_float4(vsPP[4], vsPP[5], vsPP[6], vsPP[7]);
        L0[3 * 128 + b0i] = make_float4(vsTT[0], vsTT[1], vsTT[2], vsTT[3]);
        L0[3 * 128 + b1i] = make_float4(vsTT[4], vsTT[5], vsTT[6], vsTT[7]);
        L0[4 * 128 + b0i] = make_float4(vsPT[0], vsPT[1], vsPT[2], vsPT[3]);
        L0[4 * 128 + b1i] = make_float4(vsPT[4], vsPT[5], vsPT[6], vsPT[7]);
        __syncthreads();

        // horizontal sliding sums: lane reads 24 floats (blocks 2c-2..2c+3) per q
        float Hq[5][8];
        #pragma unroll
        for (int q = 0; q < 5; ++q) {
            const float4* Lq = reinterpret_cast<const float4*>(L) + q * 128;
            float f[24];
            #pragma unroll
            for (int j = 0; j < 6; ++j) {
                int B = 2 * c - 2 + j;
                int Bc = B < 0 ? 0 : (B > 127 ? 127 : B);
                float4 v = Lq[swz(Bc)];
                if ((unsigned)B > 127u) { v.x = 0; v.y = 0; v.z = 0; v.w = 0; }  // zero-pad
                f[4 * j + 0] = v.x; f[4 * j + 1] = v.y; f[4 * j + 2] = v.z; f[4 * j + 3] = v.w;
            }
            float s = f[3];
            #pragma unroll
            for (int k = 4; k <= 13; ++k) s += f[k];
            Hq[q][0] = s;
            #pragma unroll
            for (int i = 1; i < 8; ++i) { s = s - f[i + 2] + f[i + 13]; Hq[q][i] = s; }
        }

        constexpr float inv = 1.0f / 121.0f;
        #pragma unroll
        for (int i = 0; i < 8; ++i) {
            float mup = Hq[0][i] * inv, mut = Hq[1][i] * inv;
            float spp = fmaxf(Hq[2][i] * inv - mup * mup, 0.0f);
            float stt = fmaxf(Hq[3][i] * inv - mut * mut, 0.0f);
            float spt = Hq[4][i] * inv - mup * mut;
            float num = (2.0f * mup * mut + c1) * (2.0f * spt + c2);
            float den = (mup * mup + mut * mut + c1) * (spp + stt + c2);
            float ssim = __fdividef(num, den + 1e-6f);
            lsum += fmaxf((1.0f - ssim) * 0.5f, 0.0f);
        }
        __syncthreads();
        acc(orow - 5, -1.0f);  // drop top row of window
    }

    #pragma unroll
    for (int off = 32; off; off >>= 1) lsum += __shfl_down(lsum, off);
    if (c == 0) red[wid] = lsum;
    __syncthreads();
    if (threadIdx.x == 0) parts[bx] = (red[0] + red[1]) + (red[2] + red[3]);
}

// ---------------- kernel 4: deterministic final reduce ----------------
__global__ void finish(const float* __restrict__ parts, float* __restrict__ out,
                       int n, float invN) {
    float s = 0.0f;
    for (int i = threadIdx.x; i < n; i += 256) s += parts[i];
    #pragma unroll
    for (int off = 32; off; off >>= 1) s += __shfl_down(s, off);
    __shared__ float sw[4];
    int wid = threadIdx.x >> 6, lane = threadIdx.x & 63;
    if (lane == 0) sw[wid] = s;
    __syncthreads();
    if (threadIdx.x == 0) out[0] = ((sw[0] + sw[1]) + (sw[2] + sw[3])) * invN;
}

extern "C" void kernel_launch(void* const* d_in, const int* in_sizes, int n_in,
                              void* d_out, int out_size, void* d_ws, size_t ws_size,
                              hipStream_t stream) {
    const float* pred = (const float*)d_in[0];
    const float* targ = (const float*)d_in[1];
    float* out = (float*)d_out;
    int planes = in_sizes[0] / PLANE;  // 96
    int G = planes * 8;                // 768 blocks

    float* ws   = (float*)d_ws;
    float* pmx  = ws;                  // G
    float* pmn  = ws + G;              // G
    float* c1s  = ws + 2 * G;          // planes
    float* c2s  = ws + 2 * G + planes; // planes
    float* prts = ws + 2 * G + 2 * planes;  // G

    minmax_part<<<G, 256, 0, stream>>>(pred, targ, pmx, pmn);
    minmax_fin<<<(planes + 127) / 128, 128, 0, stream>>>(pmx, pmn, c1s, c2s, planes);
    ssim_main<<<G, 256, 0, stream>>>(pred, targ, c1s, c2s, prts);
    float invN = 1.0f / ((float)planes * (float)PLANE);
    finish<<<1, 256, 0, stream>>>(prts, out, G, invN);
}